// Round 7
// baseline (194.775 us; speedup 1.0000x reference)
//
#include <hip/hip_runtime.h>
#include <math.h>

#define B 64
#define TU 128
#define TZ 16
#define V 32000
#define H 512
#define E 256
#define EPSC 1e-10f
#define KMZ 250   // k_muls split-K chunks (K=128 each)

typedef __attribute__((ext_vector_type(8))) short bf16x8;
typedef __attribute__((ext_vector_type(4))) float f32x4;
#define MFMA16(a, b, c) __builtin_amdgcn_mfma_f32_16x16x32_bf16((a), (b), (c), 0, 0, 0)

union U8 { uint4 u; bf16x8 b; };

__device__ __forceinline__ unsigned short f2bf(float f) {
  unsigned u = __float_as_uint(f);
  u += 0x7FFFu + ((u >> 16) & 1u);
  return (unsigned short)(u >> 16);
}
__device__ __forceinline__ unsigned pack2(float a, float b) {
  return (unsigned)f2bf(a) | ((unsigned)f2bf(b) << 16);
}

// stage a 64x512-short (bf16) strip into LDS [64][520]
__device__ __forceinline__ void stage64x512(unsigned short* __restrict__ dst,
                                            const unsigned short* __restrict__ src)
{
  const int tid = threadIdx.x;
#pragma unroll
  for (int j = 0; j < 16; ++j) {
    const int f = j * 256 + tid;
    const int s = f * 8;
    const int row = s >> 9, col = s & 511;
    *(uint4*)&dst[row * 520 + col] = *(const uint4*)&src[s];
  }
}

// stage a 64x512-f32 strip into LDS [64][520] as bf16 (inline convert)
__device__ __forceinline__ void stage64x512_f32(unsigned short* __restrict__ dst,
                                                const float* __restrict__ src)
{
  const int tid = threadIdx.x;
#pragma unroll
  for (int j = 0; j < 16; ++j) {
    const int f = j * 256 + tid;
    const int s = f * 8;
    const int row = s >> 9, col = s & 511;
    float4 a = *(const float4*)&src[s];
    float4 b = *(const float4*)&src[s + 4];
    uint4 o;
    o.x = pack2(a.x, a.y); o.y = pack2(a.z, a.w);
    o.z = pack2(b.x, b.y); o.w = pack2(b.z, b.w);
    *(uint4*)&dst[row * 520 + col] = o;
  }
}

// ---------------------------------------------------------------------------
// f32 64xN GEMM body (M=64): C(64,N) = A(64,K)@Bm(N,K)^T + bias; one n-tile nb
// ---------------------------------------------------------------------------
__device__ void gemm64_body(const float* __restrict__ A, int lda,
                            const float* __restrict__ Bm, int ldb,
                            const float* __restrict__ bias,
                            float* __restrict__ C, int ldc,
                            int iters, int nb)
{
  __shared__ float As[64][33];
  __shared__ float Bs[64][33];
  const int tid = threadIdx.x;
  const int n0 = nb * 64;
  const int tv = tid & 15, tb = tid >> 4;
  const int lr = tid >> 3;
  const int lc = (tid & 7) << 2;
  float acc[4][4] = {};

  for (int it = 0; it < iters; ++it) {
    const int kb = it * 32;
    float4 a0 = *(const float4*)&A[(size_t)lr * lda + kb + lc];
    float4 a1 = *(const float4*)&A[(size_t)(lr + 32) * lda + kb + lc];
    float4 b0 = *(const float4*)&Bm[(size_t)(n0 + lr) * ldb + kb + lc];
    float4 b1 = *(const float4*)&Bm[(size_t)(n0 + lr + 32) * ldb + kb + lc];
    __syncthreads();
    As[lr][lc] = a0.x; As[lr][lc + 1] = a0.y; As[lr][lc + 2] = a0.z; As[lr][lc + 3] = a0.w;
    As[lr + 32][lc] = a1.x; As[lr + 32][lc + 1] = a1.y; As[lr + 32][lc + 2] = a1.z; As[lr + 32][lc + 3] = a1.w;
    Bs[lr][lc] = b0.x; Bs[lr][lc + 1] = b0.y; Bs[lr][lc + 2] = b0.z; Bs[lr][lc + 3] = b0.w;
    Bs[lr + 32][lc] = b1.x; Bs[lr + 32][lc + 1] = b1.y; Bs[lr + 32][lc + 2] = b1.z; Bs[lr + 32][lc + 3] = b1.w;
    __syncthreads();
#pragma unroll
    for (int kk = 0; kk < 32; ++kk) {
      float av[4], bv[4];
#pragma unroll
      for (int i = 0; i < 4; ++i) av[i] = As[tb * 4 + i][kk];
#pragma unroll
      for (int j = 0; j < 4; ++j) bv[j] = Bs[tv * 4 + j][kk];
#pragma unroll
      for (int i = 0; i < 4; ++i)
#pragma unroll
        for (int j = 0; j < 4; ++j) acc[i][j] += av[i] * bv[j];
    }
  }
#pragma unroll
  for (int i = 0; i < 4; ++i)
#pragma unroll
    for (int j = 0; j < 4; ++j) {
      const int n = n0 + tv * 4 + j;
      C[(size_t)(tb * 4 + i) * ldc + n] = acc[i][j] + bias[n];
    }
}

// ---------------------------------------------------------------------------
// K1: zeroing + both GRU GEMMs (49 blocks)
// zero region: us(8192) pcs(1024) Z(64) = 9280 (pmu/pls are plain-written now)
// ---------------------------------------------------------------------------
__global__ __launch_bounds__(256) void k1_prep(
    float* __restrict__ zbuf,
    const float* __restrict__ embed_z, const float* __restrict__ W_ih,
    const float* __restrict__ b_ih, float* __restrict__ gi,
    const float* __restrict__ last_hid, const float* __restrict__ W_hh,
    const float* __restrict__ b_hh, float* __restrict__ gh)
{
  const int bx = blockIdx.x;
  if (bx == 0) {
    for (int i = threadIdx.x; i < 9280; i += 256) zbuf[i] = 0.f;
  } else if (bx < 25) {
    gemm64_body(embed_z, E, W_ih, E, b_ih, gi, 1536, 8, bx - 1);
  } else {
    gemm64_body(last_hid, H, W_hh, H, b_hh, gh, 1536, 16, bx - 25);
  }
}

// ---------------------------------------------------------------------------
__global__ void gru_gates(const float* __restrict__ gi, const float* __restrict__ gh,
                          const float* __restrict__ h0, float* __restrict__ h,
                          float* __restrict__ oh1, float* __restrict__ oh2,
                          unsigned short* __restrict__ hbf)
{
  const int b = blockIdx.x, k = threadIdx.x;  // 512 threads
  const float ir = gi[b * 1536 + k], iz = gi[b * 1536 + 512 + k], in_ = gi[b * 1536 + 1024 + k];
  const float hr = gh[b * 1536 + k], hz = gh[b * 1536 + 512 + k], hn = gh[b * 1536 + 1024 + k];
  const float r = 1.f / (1.f + __expf(-(ir + hr)));
  const float z = 1.f / (1.f + __expf(-(iz + hz)));
  const float n = tanhf(in_ + r * hn);
  const float hv = (1.f - z) * n + z * h0[b * H + k];
  h[b * H + k] = hv;
  oh1[b * H + k] = hv;
  oh2[b * H + k] = hv;
  hbf[b * H + k] = f2bf(hv);
}

// ---------------------------------------------------------------------------
// us body (f32 inputs): tanh(A@W^T+b) dot h; A streamed f32->bf16 in-register,
// W-strip staged f32->bf16 into LDS. Wave owns 32 rows x 64 cols.
// ---------------------------------------------------------------------------
__device__ void us_body_f32(unsigned short* __restrict__ Ws,
                            const float* __restrict__ A,
                            const float* __restrict__ Wm,
                            const float* __restrict__ bias,
                            const float* __restrict__ hvec,
                            float* __restrict__ outp, int T, int m0, int n0)
{
  stage64x512_f32(Ws, Wm + (size_t)n0 * 512);
  __syncthreads();

  const int tid = threadIdx.x;
  const int wave = tid >> 6, lane = tid & 63;
  const int l15 = lane & 15, l4 = lane >> 4;
  const int mbase = m0 + wave * 32;
  const float* ga = A + (size_t)(mbase + l15) * 512 + l4 * 8;

  f32x4 acc[2][4];
#pragma unroll
  for (int i = 0; i < 2; ++i)
#pragma unroll
    for (int j = 0; j < 4; ++j) acc[i][j] = (f32x4)0.f;

#pragma unroll
  for (int it = 0; it < 16; ++it) {
    bf16x8 af[2], bf[4];
#pragma unroll
    for (int i = 0; i < 2; ++i) {
      float4 a0 = *(const float4*)(ga + (size_t)i * 16 * 512 + it * 32);
      float4 a1 = *(const float4*)(ga + (size_t)i * 16 * 512 + it * 32 + 4);
      U8 u;
      u.u.x = pack2(a0.x, a0.y); u.u.y = pack2(a0.z, a0.w);
      u.u.z = pack2(a1.x, a1.y); u.u.w = pack2(a1.z, a1.w);
      af[i] = u.b;
    }
#pragma unroll
    for (int j = 0; j < 4; ++j)
      bf[j] = *(const bf16x8*)&Ws[(j * 16 + l15) * 520 + it * 32 + l4 * 8];
#pragma unroll
    for (int i = 0; i < 2; ++i)
#pragma unroll
      for (int j = 0; j < 4; ++j) acc[i][j] = MFMA16(af[i], bf[j], acc[i][j]);
  }

#pragma unroll
  for (int i = 0; i < 2; ++i) {
#pragma unroll
    for (int q = 0; q < 4; ++q) {
      const int r = mbase + i * 16 + l4 * 4 + q;   // global row = t*64 + b
      const int b = r & 63;
      float sum = 0.f;
#pragma unroll
      for (int j = 0; j < 4; ++j) {
        const int col = n0 + j * 16 + l15;
        const float x = acc[i][j][q] + bias[col];
        const float ex = __expf(2.f * x);
        const float th = 1.f - 2.f / (ex + 1.f);
        sum += th * hvec[b * H + col];
      }
      sum += __shfl_xor(sum, 1);
      sum += __shfl_xor(sum, 2);
      sum += __shfl_xor(sum, 4);
      sum += __shfl_xor(sum, 8);
      if (l15 == 0) atomicAdd(&outp[b * T + (r >> 6)], sum);
    }
  }
}

// ---------------------------------------------------------------------------
// K23: gen (500) + us (512, XCD-chunked) + pcs (64) in one grid (round-0
// proven structure).
// ---------------------------------------------------------------------------
__global__ __launch_bounds__(256) void k23(
    const unsigned short* __restrict__ h_bf, const float* __restrict__ W_w1,
    const float* __restrict__ b_w1, float* __restrict__ num,
    const float* __restrict__ u_enc, const float* __restrict__ W_p1,
    const float* __restrict__ b_p1,
    const float* __restrict__ pv_zdec, const float* __restrict__ W_p2,
    const float* __restrict__ b_p2,
    const float* __restrict__ h, float* __restrict__ us, float* __restrict__ pcs)
{
  __shared__ unsigned short sh[64 * 520];
  const int bx = blockIdx.x;
  const int tid = threadIdx.x;
  const int wave = tid >> 6, lane = tid & 63;
  const int l15 = lane & 15, l4 = lane >> 4;

  if (bx < 500) {
    const int n0 = bx * 64;
    const int nrow = n0 + (wave << 4) + l15;       // W row == output col
    const float* gw = W_w1 + (size_t)nrow * 512 + l4 * 8;

    // issue all 32 W loads first; latency overlaps the h staging below
    float4 wv[32];
#pragma unroll
    for (int it = 0; it < 16; ++it) {
      wv[2 * it]     = *(const float4*)(gw + it * 32);
      wv[2 * it + 1] = *(const float4*)(gw + it * 32 + 4);
    }

    stage64x512(sh, h_bf);
    __syncthreads();

    f32x4 acc[4];
#pragma unroll
    for (int i = 0; i < 4; ++i) acc[i] = (f32x4)0.f;

#pragma unroll
    for (int it = 0; it < 16; ++it) {
      U8 u;
      u.u.x = pack2(wv[2 * it].x, wv[2 * it].y);
      u.u.y = pack2(wv[2 * it].z, wv[2 * it].w);
      u.u.z = pack2(wv[2 * it + 1].x, wv[2 * it + 1].y);
      u.u.w = pack2(wv[2 * it + 1].z, wv[2 * it + 1].w);
#pragma unroll
      for (int i = 0; i < 4; ++i) {
        bf16x8 af = *(const bf16x8*)&sh[(i * 16 + l15) * 520 + it * 32 + l4 * 8];
        acc[i] = MFMA16(af, u.b, acc[i]);
      }
    }

    const float bv = b_w1[nrow];
#pragma unroll
    for (int i = 0; i < 4; ++i)
#pragma unroll
      for (int q = 0; q < 4; ++q) {
        const int row = i * 16 + l4 * 4 + q;
        num[(size_t)row * V + nrow] = acc[i][q] + bv;
      }
  } else if (bx < 1012) {
    const int idx = bx - 500;                  // [0,512)
    const int xcd = idx & 7, loc = idx >> 3;   // loc in [0,64)
    const int m0 = (xcd * 8 + (loc & 7)) * 128;
    const int n0 = (loc >> 3) * 64;
    us_body_f32(sh, u_enc, W_p1, b_p1, h, us, TU, m0, n0);
  } else {
    const int idx = bx - 1012;                 // [0,64)
    const int m0 = (idx & 7) * 128;
    const int n0 = (idx >> 3) * 64;
    us_body_f32(sh, pv_zdec, W_p2, b_p2, h, pcs, TZ, m0, n0);
  }
}

// ---------------------------------------------------------------------------
// smalls: per-b stabilizer K, ue = exp(us-K), base. (64 blocks x 128)
// ---------------------------------------------------------------------------
__global__ void smalls_kernel(const float* __restrict__ us, const float* __restrict__ pcs,
                              float* __restrict__ ue, float* __restrict__ base,
                              float* __restrict__ Kb)
{
  const int b = blockIdx.x, t = threadIdx.x;  // 128 threads
  __shared__ float sm[128];
  __shared__ float sK;
  const float u = us[b * TU + t];
  sm[t] = u; __syncthreads();
  for (int s = 64; s > 0; s >>= 1) {
    if (t < s) sm[t] = fmaxf(sm[t], sm[t + s]);
    __syncthreads();
  }
  if (t == 0) {
    float um = sm[0];
    float pm = -1e30f;
    for (int q = 0; q < TZ; ++q) pm = fmaxf(pm, pcs[b * TZ + q]);
    sK = fmaxf(fmaxf(um, pm), 0.0f);
  }
  __syncthreads();
  const float K = sK;
  const float e = __expf(u - K);
  ue[b * TU + t] = e;
  sm[t] = e; __syncthreads();
  for (int s = 64; s > 0; s >>= 1) {
    if (t < s) sm[t] += sm[t + s];
    __syncthreads();
  }
  if (t == 0) {
    Kb[b] = K;
    base[b] = EPSC * sm[0] + EPSC * __expf(pcs[b * TZ + 0] - K);
  }
}

// ---------------------------------------------------------------------------
// fuse3 (1024 blocks x 256): e = exp(gen-K)+base+sum_s w[s]*pv[s] into LDS;
// in-block token scatter from ue; write num (f32, unnormalized) + num_bf
// (bf16); Z partial.
// ---------------------------------------------------------------------------
__global__ __launch_bounds__(256) void fuse3(
    float* __restrict__ num, const float* __restrict__ pv,
    const float* __restrict__ pcs, const float* __restrict__ ue,
    const float* __restrict__ base, const float* __restrict__ Kb,
    const int* __restrict__ tok, float* __restrict__ Z,
    unsigned short* __restrict__ nb)
{
  __shared__ float elds[2000];
  __shared__ float red[256];
  const int bx = blockIdx.x, tid = threadIdx.x;
  const int b = bx >> 4, c = bx & 15;
  const float K = Kb[b];
  const float bs = base[b];
  float w[15];
#pragma unroll
  for (int s = 0; s < 15; ++s) w[s] = __expf(pcs[b * TZ + s + 1] - K);
  float4* nrow = (float4*)&num[(size_t)b * V];
  ushort4* brow = (ushort4*)&nb[(size_t)b * V];
  const float4* pv4 = (const float4*)pv;
  const int f0 = c * 500;
#pragma unroll
  for (int ji = 0; ji < 2; ++ji) {
    const int i = tid + ji * 256;
    if (i < 500) {
      float4 g = nrow[f0 + i];
      float4 e;
      e.x = __expf(g.x - K) + bs;
      e.y = __expf(g.y - K) + bs;
      e.z = __expf(g.z - K) + bs;
      e.w = __expf(g.w - K) + bs;
#pragma unroll
      for (int s = 0; s < 15; ++s) {
        const float4 f = pv4[(size_t)(s * B + b) * (V / 4) + f0 + i];
        e.x += w[s] * f.x; e.y += w[s] * f.y;
        e.z += w[s] * f.z; e.w += w[s] * f.w;
      }
      ((float4*)elds)[i] = e;
    }
  }
  __syncthreads();
  if (tid < TU) {
    const int tk = tok[tid * B + b];
    if (tk != 0) {
      const int lo = c * 2000;
      if (tk >= lo && tk < lo + 2000) atomicAdd(&elds[tk - lo], ue[b * TU + tid]);
    }
  }
  __syncthreads();
  float loc = 0.f;
#pragma unroll
  for (int ji = 0; ji < 2; ++ji) {
    const int i = tid + ji * 256;
    if (i < 500) {
      float4 e = ((float4*)elds)[i];
      nrow[f0 + i] = e;
      ushort4 o;
      o.x = f2bf(e.x); o.y = f2bf(e.y); o.z = f2bf(e.z); o.w = f2bf(e.w);
      brow[f0 + i] = o;
      loc += e.x + e.y + e.z + e.w;
    }
  }
  red[tid] = loc; __syncthreads();
  for (int st = 128; st > 0; st >>= 1) {
    if (tid < st) red[tid] += red[tid + st];
    __syncthreads();
  }
  if (tid == 0) atomicAdd(&Z[b], red[0]);
}

// ---------------------------------------------------------------------------
// normalize in place (-> proba output); bf16 copy already made by fuse3
// ---------------------------------------------------------------------------
__global__ __launch_bounds__(256) void norm2(float* __restrict__ num,
                                             const float* __restrict__ Z)
{
  const int b = blockIdx.y;
  const int i4 = blockIdx.x * 256 + threadIdx.x;
  if (i4 >= V / 4) return;
  const float r = 1.0f / Z[b];
  float4* row = (float4*)&num[(size_t)b * V];
  float4 v = row[i4];
  v.x *= r; v.y *= r; v.z *= r; v.w *= r;
  row[i4] = v;
}

// ---------------------------------------------------------------------------
// k_muls: num_bf(64,V unnormalized) @ {W_mu,W_ls}(256,V)^T.
// Grid (2,2,250) = 1000 blocks; NO atomics: each (y,z) block writes its own
// 64x128 f32 partial stripe (pO + z*B*E). final2 tree-reduces the stripes.
// ---------------------------------------------------------------------------
__global__ __launch_bounds__(256, 2) void k_muls(
    const unsigned short* __restrict__ Ab,
    const float* __restrict__ Wmu, const float* __restrict__ Wls,
    float* __restrict__ pmu, float* __restrict__ pls)
{
  const int tid = threadIdx.x;
  const int wave = tid >> 6, lane = tid & 63;
  const int l15 = lane & 15, l4 = lane >> 4;
  const float* gW = blockIdx.y ? Wls : Wmu;
  float* pO = (blockIdx.y ? pls : pmu) + (size_t)blockIdx.z * (B * E);
  const int kb0 = blockIdx.z * 128;
  const int c0 = blockIdx.x * 128 + wave * 32;

  const unsigned short* ga = Ab + (size_t)l15 * V + kb0 + l4 * 8;
  const float* gw0 = gW + (size_t)(c0 + l15) * V + kb0 + l4 * 8;
  const float* gw1 = gW + (size_t)(c0 + 16 + l15) * V + kb0 + l4 * 8;

  f32x4 acc[4][2];
#pragma unroll
  for (int i = 0; i < 4; ++i)
#pragma unroll
    for (int j = 0; j < 2; ++j) acc[i][j] = (f32x4)0.f;

#pragma unroll
  for (int it = 0; it < 4; ++it) {
    const int o = it * 32;
    bf16x8 af[4];
#pragma unroll
    for (int i = 0; i < 4; ++i)
      af[i] = *(const bf16x8*)(ga + (size_t)i * 16 * V + o);
    float4 a0 = *(const float4*)(gw0 + o), a1 = *(const float4*)(gw0 + o + 4);
    float4 b0 = *(const float4*)(gw1 + o), b1 = *(const float4*)(gw1 + o + 4);
    U8 u0, u1;
    u0.u.x = pack2(a0.x, a0.y); u0.u.y = pack2(a0.z, a0.w);
    u0.u.z = pack2(a1.x, a1.y); u0.u.w = pack2(a1.z, a1.w);
    u1.u.x = pack2(b0.x, b0.y); u1.u.y = pack2(b0.z, b0.w);
    u1.u.z = pack2(b1.x, b1.y); u1.u.w = pack2(b1.z, b1.w);
#pragma unroll
    for (int i = 0; i < 4; ++i) {
      acc[i][0] = MFMA16(af[i], u0.b, acc[i][0]);
      acc[i][1] = MFMA16(af[i], u1.b, acc[i][1]);
    }
  }
#pragma unroll
  for (int i = 0; i < 4; ++i)
#pragma unroll
    for (int j = 0; j < 2; ++j) {
      const int col = c0 + j * 16 + l15;
#pragma unroll
      for (int q = 0; q < 4; ++q) {
        const int row = i * 16 + l4 * 4 + q;
        pO[row * E + col] = acc[i][j][q];
      }
    }
}

// ---------------------------------------------------------------------------
// final2: sum KMZ stripes (coalesced in e), fold 1/Z + bias, reparameterize.
// (64 blocks x 256)
// ---------------------------------------------------------------------------
__global__ __launch_bounds__(256) void final2(
    const float* __restrict__ pmu, const float* __restrict__ pls,
    const float* __restrict__ Z,
    const float* __restrict__ bmu, const float* __restrict__ bls,
    const float* __restrict__ eps_r, float* __restrict__ out)
{
  const int b = blockIdx.x, e = threadIdx.x;  // 256 threads == E
  const int o = b * E + e;
  float smu = 0.f, sls = 0.f;
  for (int s = 0; s < KMZ; ++s) {
    smu += pmu[(size_t)s * (B * E) + o];
    sls += pls[(size_t)s * (B * E) + o];
  }
  const float rz = 1.0f / Z[b];
  const float ap = smu * rz + bmu[e];
  const float ls = sls * rz + bls[e];
  out[b * E + e] = ap + __expf(ls) * eps_r[b * E + e];
  out[2129920 + b * E + e] = ap;
  out[2146304 + b * E + e] = ls;
}

// ---------------------------------------------------------------------------
extern "C" void kernel_launch(void* const* d_in, const int* in_sizes, int n_in,
                              void* d_out_v, int out_size, void* d_ws, size_t ws_size,
                              hipStream_t stream)
{
  (void)in_sizes; (void)n_in; (void)out_size; (void)ws_size;
  const float* embed_z    = (const float*)d_in[0];
  const float* last_hid   = (const float*)d_in[1];
  const float* u_enc      = (const float*)d_in[2];
  const float* pv_pz      = (const float*)d_in[3];
  const float* pv_zdec    = (const float*)d_in[4];
  const float* rand_eps   = (const float*)d_in[5];
  const int*   u_input_np = (const int*)d_in[6];
  const float* W_ih = (const float*)d_in[9];
  const float* W_hh = (const float*)d_in[10];
  const float* b_ih = (const float*)d_in[11];
  const float* b_hh = (const float*)d_in[12];
  const float* W_w1 = (const float*)d_in[13];
  const float* b_w1 = (const float*)d_in[14];
  const float* W_p1 = (const float*)d_in[15];
  const float* b_p1 = (const float*)d_in[16];
  const float* W_p2 = (const float*)d_in[17];
  const float* b_p2 = (const float*)d_in[18];
  const float* W_mu = (const float*)d_in[19];
  const float* b_mu = (const float*)d_in[20];
  const float* W_ls = (const float*)d_in[21];
  const float* b_ls = (const float*)d_in[22];
  float* d_out = (float*)d_out_v;

  float* ws   = (float*)d_ws;
  float* h    = ws;                  // 32768 floats
  float* gi   = ws + 32768;          // 98304
  float* gh   = ws + 131072;         // 98304
  // zero-region (9280 floats): us, pcs, Z contiguous
  float* us   = ws + 229376;         // 8192
  float* pcs  = ws + 237568;         // 1024
  float* Z    = ws + 238592;         // 64
  float* ue   = ws + 238656;         // 8192
  float* base = ws + 246848;         // 64
  float* Kb   = ws + 246912;         // 64
  unsigned short* h_bf   = (unsigned short*)(ws + 246976);   // 32768 ushorts
  unsigned short* num_bf = (unsigned short*)(ws + 263360);   // 2,048,000 ushorts
  float* pmu  = ws + 1287360;        // KMZ x B*E = 4,096,000 floats
  float* pls  = ws + 5383360;        // 4,096,000 floats

  float* num   = d_out + 81920;   // proba slot doubles as numerator scratch
  float* outh1 = d_out + 16384;
  float* outh2 = d_out + 49152;

  // K1: zero(us,pcs,Z) + GRU GEMMs
  k1_prep<<<dim3(49), 256, 0, stream>>>(
      us /* zero-region base */,
      embed_z, W_ih, b_ih, gi, last_hid, W_hh, b_hh, gh);

  gru_gates<<<dim3(B), 512, 0, stream>>>(gi, gh, last_hid, h, outh1, outh2, h_bf);

  // K23: gen (500) + us (512, XCD-chunked) + pcs (64)
  k23<<<dim3(1076), 256, 0, stream>>>(
      h_bf, W_w1, b_w1, num,
      u_enc, W_p1, b_p1,
      pv_zdec, W_p2, b_p2,
      h, us, pcs);

  smalls_kernel<<<dim3(B), 128, 0, stream>>>(us, pcs, ue, base, Kb);

  // fuse3: numerator (direct pv read) + in-block scatter + bf16 copy + Z
  fuse3<<<dim3(1024), 256, 0, stream>>>(num, pv_pz, pcs, ue, base, Kb,
                                        u_input_np, Z, num_bf);

  // mu/ls: deep split-K (1000 blocks), atomic-free partial stripes
  k_muls<<<dim3(2, 2, KMZ), 256, 0, stream>>>(num_bf, W_mu, W_ls, pmu, pls);

  final2<<<dim3(B), 256, 0, stream>>>(pmu, pls, Z, b_mu, b_ls, rand_eps, d_out);

  // proba output (independent tail)
  norm2<<<dim3(32, B), 256, 0, stream>>>(num, Z);
}

// Round 8
// 166.213 us; speedup vs baseline: 1.1718x; 1.1718x over previous
//
#include <hip/hip_runtime.h>
#include <math.h>

#define B 64
#define TU 128
#define TZ 16
#define V 32000
#define H 512
#define E 256
#define EPSC 1e-10f

typedef __attribute__((ext_vector_type(8))) short bf16x8;
typedef __attribute__((ext_vector_type(4))) float f32x4;
#define MFMA16(a, b, c) __builtin_amdgcn_mfma_f32_16x16x32_bf16((a), (b), (c), 0, 0, 0)

union U8 { uint4 u; bf16x8 b; };

__device__ __forceinline__ unsigned short f2bf(float f) {
  unsigned u = __float_as_uint(f);
  u += 0x7FFFu + ((u >> 16) & 1u);
  return (unsigned short)(u >> 16);
}
__device__ __forceinline__ unsigned pack2(float a, float b) {
  return (unsigned)f2bf(a) | ((unsigned)f2bf(b) << 16);
}

// stage a 64x512-short (bf16) strip into LDS [64][520]
__device__ __forceinline__ void stage64x512(unsigned short* __restrict__ dst,
                                            const unsigned short* __restrict__ src)
{
  const int tid = threadIdx.x;
#pragma unroll
  for (int j = 0; j < 16; ++j) {
    const int f = j * 256 + tid;
    const int s = f * 8;
    const int row = s >> 9, col = s & 511;
    *(uint4*)&dst[row * 520 + col] = *(const uint4*)&src[s];
  }
}

// stage a 64x512-f32 strip into LDS [64][520] as bf16 (inline convert)
__device__ __forceinline__ void stage64x512_f32(unsigned short* __restrict__ dst,
                                                const float* __restrict__ src)
{
  const int tid = threadIdx.x;
#pragma unroll
  for (int j = 0; j < 16; ++j) {
    const int f = j * 256 + tid;
    const int s = f * 8;
    const int row = s >> 9, col = s & 511;
    float4 a = *(const float4*)&src[s];
    float4 b = *(const float4*)&src[s + 4];
    uint4 o;
    o.x = pack2(a.x, a.y); o.y = pack2(a.z, a.w);
    o.z = pack2(b.x, b.y); o.w = pack2(b.z, b.w);
    *(uint4*)&dst[row * 520 + col] = o;
  }
}

// ---------------------------------------------------------------------------
// f32 64xN GEMM body (M=64): C(64,N) = A(64,K)@Bm(N,K)^T + bias; one n-tile nb
// ---------------------------------------------------------------------------
__device__ void gemm64_body(const float* __restrict__ A, int lda,
                            const float* __restrict__ Bm, int ldb,
                            const float* __restrict__ bias,
                            float* __restrict__ C, int ldc,
                            int iters, int nb)
{
  __shared__ float As[64][33];
  __shared__ float Bs[64][33];
  const int tid = threadIdx.x;
  const int n0 = nb * 64;
  const int tv = tid & 15, tb = tid >> 4;
  const int lr = tid >> 3;
  const int lc = (tid & 7) << 2;
  float acc[4][4] = {};

  for (int it = 0; it < iters; ++it) {
    const int kb = it * 32;
    float4 a0 = *(const float4*)&A[(size_t)lr * lda + kb + lc];
    float4 a1 = *(const float4*)&A[(size_t)(lr + 32) * lda + kb + lc];
    float4 b0 = *(const float4*)&Bm[(size_t)(n0 + lr) * ldb + kb + lc];
    float4 b1 = *(const float4*)&Bm[(size_t)(n0 + lr + 32) * ldb + kb + lc];
    __syncthreads();
    As[lr][lc] = a0.x; As[lr][lc + 1] = a0.y; As[lr][lc + 2] = a0.z; As[lr][lc + 3] = a0.w;
    As[lr + 32][lc] = a1.x; As[lr + 32][lc + 1] = a1.y; As[lr + 32][lc + 2] = a1.z; As[lr + 32][lc + 3] = a1.w;
    Bs[lr][lc] = b0.x; Bs[lr][lc + 1] = b0.y; Bs[lr][lc + 2] = b0.z; Bs[lr][lc + 3] = b0.w;
    Bs[lr + 32][lc] = b1.x; Bs[lr + 32][lc + 1] = b1.y; Bs[lr + 32][lc + 2] = b1.z; Bs[lr + 32][lc + 3] = b1.w;
    __syncthreads();
#pragma unroll
    for (int kk = 0; kk < 32; ++kk) {
      float av[4], bv[4];
#pragma unroll
      for (int i = 0; i < 4; ++i) av[i] = As[tb * 4 + i][kk];
#pragma unroll
      for (int j = 0; j < 4; ++j) bv[j] = Bs[tv * 4 + j][kk];
#pragma unroll
      for (int i = 0; i < 4; ++i)
#pragma unroll
        for (int j = 0; j < 4; ++j) acc[i][j] += av[i] * bv[j];
    }
  }
#pragma unroll
  for (int i = 0; i < 4; ++i)
#pragma unroll
    for (int j = 0; j < 4; ++j) {
      const int n = n0 + tv * 4 + j;
      C[(size_t)(tb * 4 + i) * ldc + n] = acc[i][j] + bias[n];
    }
}

// ---------------------------------------------------------------------------
// K1: zeroing + both GRU GEMMs (49 blocks)
// zero region: us(8192) pcs(1024) Z(64) pmu(65536) pls(65536) = 140352
// ---------------------------------------------------------------------------
__global__ __launch_bounds__(256) void k1_prep(
    float* __restrict__ zbuf,
    const float* __restrict__ embed_z, const float* __restrict__ W_ih,
    const float* __restrict__ b_ih, float* __restrict__ gi,
    const float* __restrict__ last_hid, const float* __restrict__ W_hh,
    const float* __restrict__ b_hh, float* __restrict__ gh)
{
  const int bx = blockIdx.x;
  if (bx == 0) {
    for (int i = threadIdx.x; i < 140352; i += 256) zbuf[i] = 0.f;
  } else if (bx < 25) {
    gemm64_body(embed_z, E, W_ih, E, b_ih, gi, 1536, 8, bx - 1);
  } else {
    gemm64_body(last_hid, H, W_hh, H, b_hh, gh, 1536, 16, bx - 25);
  }
}

// ---------------------------------------------------------------------------
__global__ void gru_gates(const float* __restrict__ gi, const float* __restrict__ gh,
                          const float* __restrict__ h0, float* __restrict__ h,
                          float* __restrict__ oh1, float* __restrict__ oh2,
                          unsigned short* __restrict__ hbf)
{
  const int b = blockIdx.x, k = threadIdx.x;  // 512 threads
  const float ir = gi[b * 1536 + k], iz = gi[b * 1536 + 512 + k], in_ = gi[b * 1536 + 1024 + k];
  const float hr = gh[b * 1536 + k], hz = gh[b * 1536 + 512 + k], hn = gh[b * 1536 + 1024 + k];
  const float r = 1.f / (1.f + __expf(-(ir + hr)));
  const float z = 1.f / (1.f + __expf(-(iz + hz)));
  const float n = tanhf(in_ + r * hn);
  const float hv = (1.f - z) * n + z * h0[b * H + k];
  h[b * H + k] = hv;
  oh1[b * H + k] = hv;
  oh2[b * H + k] = hv;
  hbf[b * H + k] = f2bf(hv);
}

// ---------------------------------------------------------------------------
// us body (f32 inputs): tanh(A@W^T+b) dot h; A streamed f32->bf16 in-register,
// W-strip staged f32->bf16 into LDS. Wave owns 32 rows x 64 cols.
// ---------------------------------------------------------------------------
__device__ void us_body_f32(unsigned short* __restrict__ Ws,
                            const float* __restrict__ A,
                            const float* __restrict__ Wm,
                            const float* __restrict__ bias,
                            const float* __restrict__ hvec,
                            float* __restrict__ outp, int T, int m0, int n0)
{
  stage64x512_f32(Ws, Wm + (size_t)n0 * 512);
  __syncthreads();

  const int tid = threadIdx.x;
  const int wave = tid >> 6, lane = tid & 63;
  const int l15 = lane & 15, l4 = lane >> 4;
  const int mbase = m0 + wave * 32;
  const float* ga = A + (size_t)(mbase + l15) * 512 + l4 * 8;

  f32x4 acc[2][4];
#pragma unroll
  for (int i = 0; i < 2; ++i)
#pragma unroll
    for (int j = 0; j < 4; ++j) acc[i][j] = (f32x4)0.f;

#pragma unroll
  for (int it = 0; it < 16; ++it) {
    bf16x8 af[2], bf[4];
#pragma unroll
    for (int i = 0; i < 2; ++i) {
      float4 a0 = *(const float4*)(ga + (size_t)i * 16 * 512 + it * 32);
      float4 a1 = *(const float4*)(ga + (size_t)i * 16 * 512 + it * 32 + 4);
      U8 u;
      u.u.x = pack2(a0.x, a0.y); u.u.y = pack2(a0.z, a0.w);
      u.u.z = pack2(a1.x, a1.y); u.u.w = pack2(a1.z, a1.w);
      af[i] = u.b;
    }
#pragma unroll
    for (int j = 0; j < 4; ++j)
      bf[j] = *(const bf16x8*)&Ws[(j * 16 + l15) * 520 + it * 32 + l4 * 8];
#pragma unroll
    for (int i = 0; i < 2; ++i)
#pragma unroll
      for (int j = 0; j < 4; ++j) acc[i][j] = MFMA16(af[i], bf[j], acc[i][j]);
  }

#pragma unroll
  for (int i = 0; i < 2; ++i) {
#pragma unroll
    for (int q = 0; q < 4; ++q) {
      const int r = mbase + i * 16 + l4 * 4 + q;   // global row = t*64 + b
      const int b = r & 63;
      float sum = 0.f;
#pragma unroll
      for (int j = 0; j < 4; ++j) {
        const int col = n0 + j * 16 + l15;
        const float x = acc[i][j][q] + bias[col];
        const float ex = __expf(2.f * x);
        const float th = 1.f - 2.f / (ex + 1.f);
        sum += th * hvec[b * H + col];
      }
      sum += __shfl_xor(sum, 1);
      sum += __shfl_xor(sum, 2);
      sum += __shfl_xor(sum, 4);
      sum += __shfl_xor(sum, 8);
      if (l15 == 0) atomicAdd(&outp[b * T + (r >> 6)], sum);
    }
  }
}

// ---------------------------------------------------------------------------
// K23: gen (500) + us (512, XCD-chunked) + pcs (64) in one grid.
// ---------------------------------------------------------------------------
__global__ __launch_bounds__(256) void k23(
    const unsigned short* __restrict__ h_bf, const float* __restrict__ W_w1,
    const float* __restrict__ b_w1, float* __restrict__ num,
    const float* __restrict__ u_enc, const float* __restrict__ W_p1,
    const float* __restrict__ b_p1,
    const float* __restrict__ pv_zdec, const float* __restrict__ W_p2,
    const float* __restrict__ b_p2,
    const float* __restrict__ h, float* __restrict__ us, float* __restrict__ pcs)
{
  __shared__ unsigned short sh[64 * 520];
  const int bx = blockIdx.x;
  const int tid = threadIdx.x;
  const int wave = tid >> 6, lane = tid & 63;
  const int l15 = lane & 15, l4 = lane >> 4;

  if (bx < 500) {
    const int n0 = bx * 64;
    const int nrow = n0 + (wave << 4) + l15;       // W row == output col
    const float* gw = W_w1 + (size_t)nrow * 512 + l4 * 8;

    // issue all 32 W loads first; latency overlaps the h staging below
    float4 wv[32];
#pragma unroll
    for (int it = 0; it < 16; ++it) {
      wv[2 * it]     = *(const float4*)(gw + it * 32);
      wv[2 * it + 1] = *(const float4*)(gw + it * 32 + 4);
    }

    stage64x512(sh, h_bf);
    __syncthreads();

    f32x4 acc[4];
#pragma unroll
    for (int i = 0; i < 4; ++i) acc[i] = (f32x4)0.f;

#pragma unroll
    for (int it = 0; it < 16; ++it) {
      U8 u;
      u.u.x = pack2(wv[2 * it].x, wv[2 * it].y);
      u.u.y = pack2(wv[2 * it].z, wv[2 * it].w);
      u.u.z = pack2(wv[2 * it + 1].x, wv[2 * it + 1].y);
      u.u.w = pack2(wv[2 * it + 1].z, wv[2 * it + 1].w);
#pragma unroll
      for (int i = 0; i < 4; ++i) {
        bf16x8 af = *(const bf16x8*)&sh[(i * 16 + l15) * 520 + it * 32 + l4 * 8];
        acc[i] = MFMA16(af, u.b, acc[i]);
      }
    }

    const float bv = b_w1[nrow];
#pragma unroll
    for (int i = 0; i < 4; ++i)
#pragma unroll
      for (int q = 0; q < 4; ++q) {
        const int row = i * 16 + l4 * 4 + q;
        num[(size_t)row * V + nrow] = acc[i][q] + bv;
      }
  } else if (bx < 1012) {
    const int idx = bx - 500;                  // [0,512)
    const int xcd = idx & 7, loc = idx >> 3;   // loc in [0,64)
    const int m0 = (xcd * 8 + (loc & 7)) * 128;
    const int n0 = (loc >> 3) * 64;
    us_body_f32(sh, u_enc, W_p1, b_p1, h, us, TU, m0, n0);
  } else {
    const int idx = bx - 1012;                 // [0,64)
    const int m0 = (idx & 7) * 128;
    const int n0 = (idx >> 3) * 64;
    us_body_f32(sh, pv_zdec, W_p2, b_p2, h, pcs, TZ, m0, n0);
  }
}

// ---------------------------------------------------------------------------
// fuse3 (1024 blocks x 256): inline smalls (K, base, ue) + numerator
// e = exp(gen-K)+base+sum_s w[s]*pv[s] into LDS + in-block token scatter +
// num (f32, unnormalized) + num_bf (bf16) + Z partial.
// ---------------------------------------------------------------------------
__global__ __launch_bounds__(256) void fuse3(
    float* __restrict__ num, const float* __restrict__ pv,
    const float* __restrict__ pcs, const float* __restrict__ us,
    const int* __restrict__ tok, float* __restrict__ Z,
    unsigned short* __restrict__ nb)
{
  __shared__ float elds[2000];
  __shared__ float red[256];
  __shared__ float sK;
  const int bx = blockIdx.x, tid = threadIdx.x;
  const int b = bx >> 4, c = bx & 15;

  // inline smalls: K = max(max_t us, max_q pcs, 0)
  float m = (tid < TU) ? us[b * TU + tid] : -1e30f;
  red[tid] = m; __syncthreads();
  for (int s = 128; s > 0; s >>= 1) {
    if (tid < s) red[tid] = fmaxf(red[tid], red[tid + s]);
    __syncthreads();
  }
  if (tid == 0) {
    float pm = -1e30f;
    for (int q = 0; q < TZ; ++q) pm = fmaxf(pm, pcs[b * TZ + q]);
    sK = fmaxf(fmaxf(red[0], pm), 0.0f);
  }
  __syncthreads();
  const float K = sK;
  // ue (per-thread) + base = EPS*sum(ue) + EPS*exp(pcs0-K)
  float e_t = (tid < TU) ? __expf(us[b * TU + tid] - K) : 0.f;
  red[tid] = e_t; __syncthreads();
  for (int s = 128; s > 0; s >>= 1) {
    if (tid < s) red[tid] += red[tid + s];
    __syncthreads();
  }
  const float bs = EPSC * red[0] + EPSC * __expf(pcs[b * TZ] - K);

  float w[15];
#pragma unroll
  for (int s = 0; s < 15; ++s) w[s] = __expf(pcs[b * TZ + s + 1] - K);
  float4* nrow = (float4*)&num[(size_t)b * V];
  ushort4* brow = (ushort4*)&nb[(size_t)b * V];
  const float4* pv4 = (const float4*)pv;
  const int f0 = c * 500;
#pragma unroll
  for (int ji = 0; ji < 2; ++ji) {
    const int i = tid + ji * 256;
    if (i < 500) {
      float4 g = nrow[f0 + i];
      float4 e;
      e.x = __expf(g.x - K) + bs;
      e.y = __expf(g.y - K) + bs;
      e.z = __expf(g.z - K) + bs;
      e.w = __expf(g.w - K) + bs;
#pragma unroll
      for (int s = 0; s < 15; ++s) {
        const float4 f = pv4[(size_t)(s * B + b) * (V / 4) + f0 + i];
        e.x += w[s] * f.x; e.y += w[s] * f.y;
        e.z += w[s] * f.z; e.w += w[s] * f.w;
      }
      ((float4*)elds)[i] = e;
    }
  }
  __syncthreads();
  if (tid < TU) {
    const int tk = tok[tid * B + b];
    if (tk != 0) {
      const int lo = c * 2000;
      if (tk >= lo && tk < lo + 2000) atomicAdd(&elds[tk - lo], e_t);
    }
  }
  __syncthreads();
  float loc = 0.f;
#pragma unroll
  for (int ji = 0; ji < 2; ++ji) {
    const int i = tid + ji * 256;
    if (i < 500) {
      float4 e = ((float4*)elds)[i];
      nrow[f0 + i] = e;
      ushort4 o;
      o.x = f2bf(e.x); o.y = f2bf(e.y); o.z = f2bf(e.z); o.w = f2bf(e.w);
      brow[f0 + i] = o;
      loc += e.x + e.y + e.z + e.w;
    }
  }
  red[tid] = loc; __syncthreads();
  for (int st = 128; st > 0; st >>= 1) {
    if (tid < st) red[tid] += red[tid + st];
    __syncthreads();
  }
  if (tid == 0) atomicAdd(&Z[b], red[0]);
}

// ---------------------------------------------------------------------------
// k_muls (round-6 proven form) + norm2 folded in as extra blocks.
// bx < 1000: GEMM chunk (x = bx&1, y = (bx>>1)&1, z = bx>>2), K-chunk 128,
//            atomicAdd into 4 stripes (z&3).
// bx >= 1000: norm blocks (2048): normalize num in place (proba output).
// ---------------------------------------------------------------------------
__global__ __launch_bounds__(256, 2) void k_muls(
    const unsigned short* __restrict__ Ab,
    const float* __restrict__ Wmu, const float* __restrict__ Wls,
    float* __restrict__ pmu, float* __restrict__ pls,
    float* __restrict__ num, const float* __restrict__ Z)
{
  const int bx = blockIdx.x;
  const int tid = threadIdx.x;
  if (bx < 1000) {
    const int x = bx & 1, y = (bx >> 1) & 1, z = bx >> 2;
    const int wave = tid >> 6, lane = tid & 63;
    const int l15 = lane & 15, l4 = lane >> 4;
    const float* gW = y ? Wls : Wmu;
    float* pO = (y ? pls : pmu) + (z & 3) * (B * E);
    const int kb0 = z * 128;
    const int c0 = x * 128 + wave * 32;

    const unsigned short* ga = Ab + (size_t)l15 * V + kb0 + l4 * 8;
    const float* gw0 = gW + (size_t)(c0 + l15) * V + kb0 + l4 * 8;
    const float* gw1 = gW + (size_t)(c0 + 16 + l15) * V + kb0 + l4 * 8;

    f32x4 acc[4][2];
#pragma unroll
    for (int i = 0; i < 4; ++i)
#pragma unroll
      for (int j = 0; j < 2; ++j) acc[i][j] = (f32x4)0.f;

#pragma unroll
    for (int it = 0; it < 4; ++it) {
      const int o = it * 32;
      bf16x8 af[4];
#pragma unroll
      for (int i = 0; i < 4; ++i)
        af[i] = *(const bf16x8*)(ga + (size_t)i * 16 * V + o);
      float4 a0 = *(const float4*)(gw0 + o), a1 = *(const float4*)(gw0 + o + 4);
      float4 b0 = *(const float4*)(gw1 + o), b1 = *(const float4*)(gw1 + o + 4);
      U8 u0, u1;
      u0.u.x = pack2(a0.x, a0.y); u0.u.y = pack2(a0.z, a0.w);
      u0.u.z = pack2(a1.x, a1.y); u0.u.w = pack2(a1.z, a1.w);
      u1.u.x = pack2(b0.x, b0.y); u1.u.y = pack2(b0.z, b0.w);
      u1.u.z = pack2(b1.x, b1.y); u1.u.w = pack2(b1.z, b1.w);
#pragma unroll
      for (int i = 0; i < 4; ++i) {
        acc[i][0] = MFMA16(af[i], u0.b, acc[i][0]);
        acc[i][1] = MFMA16(af[i], u1.b, acc[i][1]);
      }
    }
#pragma unroll
    for (int i = 0; i < 4; ++i)
#pragma unroll
      for (int j = 0; j < 2; ++j) {
        const int col = c0 + j * 16 + l15;
#pragma unroll
        for (int q = 0; q < 4; ++q) {
          const int row = i * 16 + l4 * 4 + q;
          atomicAdd(&pO[row * E + col], acc[i][j][q]);
        }
      }
  } else {
    const int idx = bx - 1000;               // [0,2048): 32 chunks x 64 b
    const int b = idx >> 5;
    const int i4 = (idx & 31) * 256 + tid;
    if (i4 < V / 4) {
      const float r = 1.0f / Z[b];
      float4* row = (float4*)&num[(size_t)b * V];
      float4 v = row[i4];
      v.x *= r; v.y *= r; v.z *= r; v.w *= r;
      row[i4] = v;
    }
  }
}

// ---------------------------------------------------------------------------
// final2: sum 4 stripes, fold 1/Z + bias, reparameterize. (64 blocks x 256)
// ---------------------------------------------------------------------------
__global__ void final2(const float* __restrict__ pmu, const float* __restrict__ pls,
                       const float* __restrict__ Z,
                       const float* __restrict__ bmu, const float* __restrict__ bls,
                       const float* __restrict__ eps_r, float* __restrict__ out)
{
  const int b = blockIdx.x, e = threadIdx.x;  // 256 threads == E
  float smu = 0.f, sls = 0.f;
#pragma unroll
  for (int s = 0; s < 4; ++s) {
    smu += pmu[s * (B * E) + b * E + e];
    sls += pls[s * (B * E) + b * E + e];
  }
  const float rz = 1.0f / Z[b];
  const float ap = smu * rz + bmu[e];
  const float ls = sls * rz + bls[e];
  out[b * E + e] = ap + __expf(ls) * eps_r[b * E + e];
  out[2129920 + b * E + e] = ap;
  out[2146304 + b * E + e] = ls;
}

// ---------------------------------------------------------------------------
extern "C" void kernel_launch(void* const* d_in, const int* in_sizes, int n_in,
                              void* d_out_v, int out_size, void* d_ws, size_t ws_size,
                              hipStream_t stream)
{
  (void)in_sizes; (void)n_in; (void)out_size; (void)ws_size;
  const float* embed_z    = (const float*)d_in[0];
  const float* last_hid   = (const float*)d_in[1];
  const float* u_enc      = (const float*)d_in[2];
  const float* pv_pz      = (const float*)d_in[3];
  const float* pv_zdec    = (const float*)d_in[4];
  const float* rand_eps   = (const float*)d_in[5];
  const int*   u_input_np = (const int*)d_in[6];
  const float* W_ih = (const float*)d_in[9];
  const float* W_hh = (const float*)d_in[10];
  const float* b_ih = (const float*)d_in[11];
  const float* b_hh = (const float*)d_in[12];
  const float* W_w1 = (const float*)d_in[13];
  const float* b_w1 = (const float*)d_in[14];
  const float* W_p1 = (const float*)d_in[15];
  const float* b_p1 = (const float*)d_in[16];
  const float* W_p2 = (const float*)d_in[17];
  const float* b_p2 = (const float*)d_in[18];
  const float* W_mu = (const float*)d_in[19];
  const float* b_mu = (const float*)d_in[20];
  const float* W_ls = (const float*)d_in[21];
  const float* b_ls = (const float*)d_in[22];
  float* d_out = (float*)d_out_v;

  float* ws   = (float*)d_ws;
  float* h    = ws;                  // 32768 floats
  float* gi   = ws + 32768;          // 98304
  float* gh   = ws + 131072;         // 98304
  // zero-region (140352 floats): us, pcs, Z, pmu(4 stripes), pls(4 stripes)
  float* us   = ws + 229376;         // 8192
  float* pcs  = ws + 237568;         // 1024
  float* Z    = ws + 238592;         // 64
  float* pmu  = ws + 238656;         // 65536 (4 x B*E)
  float* pls  = ws + 304192;         // 65536 (4 x B*E)
  unsigned short* h_bf   = (unsigned short*)(ws + 369728);   // 32768 ushorts
  unsigned short* num_bf = (unsigned short*)(ws + 386112);   // 2,048,000 ushorts

  float* num   = d_out + 81920;   // proba slot doubles as numerator scratch
  float* outh1 = d_out + 16384;
  float* outh2 = d_out + 49152;

  // K1: zero(us,pcs,Z,pmu,pls) + GRU GEMMs
  k1_prep<<<dim3(49), 256, 0, stream>>>(
      us /* zero-region base */,
      embed_z, W_ih, b_ih, gi, last_hid, W_hh, b_hh, gh);

  gru_gates<<<dim3(B), 512, 0, stream>>>(gi, gh, last_hid, h, outh1, outh2, h_bf);

  // K23: gen (500) + us (512, XCD-chunked) + pcs (64)
  k23<<<dim3(1076), 256, 0, stream>>>(
      h_bf, W_w1, b_w1, num,
      u_enc, W_p1, b_p1,
      pv_zdec, W_p2, b_p2,
      h, us, pcs);

  // fuse3: inline smalls + numerator + scatter + bf16 copy + Z
  fuse3<<<dim3(1024), 256, 0, stream>>>(num, pv_pz, pcs, us,
                                        u_input_np, Z, num_bf);

  // mu/ls GEMM (1000 blocks, atomic 4-stripe) + norm2 folded in (2048 blocks)
  k_muls<<<dim3(3048), 256, 0, stream>>>(num_bf, W_mu, W_ls, pmu, pls, num, Z);

  final2<<<dim3(B), 256, 0, stream>>>(pmu, pls, Z, b_mu, b_ls, rand_eps, d_out);
}